// Round 8
// baseline (158.609 us; speedup 1.0000x reference)
//
#include <hip/hip_runtime.h>

#define BB 4
#define NN 2048
#define INF 256
#define HH 8
#define DD 32
#define LOG2E 1.4426950408889634f

typedef __attribute__((ext_vector_type(8))) short short8;
typedef __attribute__((ext_vector_type(4))) float f32x4;

__device__ __forceinline__ unsigned short bf16_rne(float v) {
    unsigned b = __float_as_uint(v);
    return (unsigned short)((b + 0x7fffu + ((b >> 16) & 1u)) >> 16);
}
__device__ __forceinline__ unsigned short bf16_rhu(float v) {
    return (unsigned short)((__float_as_uint(v) + 0x8000u) >> 16);
}

// wprep: we_g[16][256] fp32 (log2-scaled) + wT bf16 [h*32+d][f]. grid 32 x 256.
__global__ __launch_bounds__(256) void wprep_kernel(
    const float* __restrict__ W, const float* __restrict__ a,
    float* __restrict__ we_g, unsigned short* __restrict__ wT)
{
    const int bb = blockIdx.x, t = threadIdx.x;
    if (bb < 16) {           // we part: k = bb
        const int h = bb & 7, sel = bb >> 3;
        const float* wr = W + ((size_t)(h * INF + t)) * DD;
        const float* av = a + h * 2 * DD + sel * DD;
        float acc = 0.f;
        #pragma unroll
        for (int d = 0; d < DD; ++d) acc += wr[d] * av[d];
        we_g[bb * INF + t] = acc * LOG2E;
    }
    #pragma unroll
    for (int r2 = 0; r2 < 8; ++r2) {      // wT rows bb*8 .. bb*8+8
        int row = bb * 8 + r2;
        int h = row >> 5, d = row & 31;
        wT[row * INF + t] = bf16_rhu(W[((size_t)(h * INF + t)) * DD + d]);
    }
}

// ek: exact fp32 e-dots. 16-row tiles, grid 512 x 256.
// esrc raw (log2-scaled); ejP = pack(bf16(exp2(ej)), bf16(exp2(0.2 ej))).
__global__ __launch_bounds__(256) void ek_kernel(
    const float* __restrict__ x, const float* __restrict__ we_g,
    float* __restrict__ esrc, unsigned* __restrict__ ejP)
{
    __shared__ __align__(16) float xs[16 * 260];       // [row][f] pad 260
    __shared__ __align__(16) float weld2[16 * 260];    // [c][k*16+fi] pad 260
    const int t = threadIdx.x;
    const int tile = blockIdx.x & 127, b = blockIdx.x >> 7;
    const int n0 = tile * 16;

    #pragma unroll
    for (int p = 0; p < 4; ++p) {        // x tile: fully coalesced 1KB/instr
        int flat = p * 1024 + t * 4;
        int row = flat >> 8, col = flat & 255;
        f32x4 g = *(const f32x4*)&x[((size_t)(b * NN + n0 + row)) * INF + col];
        *(f32x4*)&xs[row * 260 + col] = g;
    }
    #pragma unroll
    for (int p = 0; p < 4; ++p) {        // weld2[c][k][fi]
        int flat = p * 1024 + t * 4;
        int k = flat >> 8, f = flat & 255;
        f32x4 g = *(const f32x4*)&we_g[flat];
        *(f32x4*)&weld2[(f >> 4) * 260 + k * 16 + (f & 15)] = g;
    }
    __syncthreads();

    const int row = t >> 4, c = t & 15;
    f32x4 xv[4];
    #pragma unroll
    for (int i = 0; i < 4; ++i)
        xv[i] = *(const f32x4*)&xs[row * 260 + c * 16 + i * 4];

    float keep = 0.f;
    #pragma unroll
    for (int k = 0; k < 16; ++k) {
        float s = 0.f;
        #pragma unroll
        for (int i = 0; i < 4; ++i) {
            f32x4 w4 = *(const f32x4*)&weld2[c * 260 + k * 16 + i * 4];
            s += xv[i][0]*w4[0] + xv[i][1]*w4[1] + xv[i][2]*w4[2] + xv[i][3]*w4[3];
        }
        s += __shfl_xor(s, 1, 64);
        s += __shfl_xor(s, 2, 64);
        s += __shfl_xor(s, 4, 64);
        s += __shfl_xor(s, 8, 64);
        keep = (c == k) ? s : keep;
    }
    const int n = n0 + row;
    if (c < 8) {
        esrc[(b * 8 + c) * NN + n] = keep;
    } else {
        float Ej  = __builtin_amdgcn_exp2f(keep);
        float Ej5 = __builtin_amdgcn_exp2f(0.2f * keep);
        ejP[(b * 8 + (c - 8)) * NN + n] =
            ((unsigned)bf16_rne(Ej) << 16) | (unsigned)bf16_rne(Ej5);
    }
}

// whk: 64 rows x 64 cols (2 heads) x K=256 MFMA GEMM, fp32 x converted in staging.
// output whT2[bh][j/8][d][8] bf16. grid 512 x 256, LDS 67KB -> 2 blocks/CU.
__global__ __launch_bounds__(256) void whk_kernel(
    const float* __restrict__ x, const unsigned short* __restrict__ wT,
    unsigned short* __restrict__ whT2)
{
    __shared__ __align__(16) unsigned short xb[64 * 264];
    __shared__ __align__(16) unsigned short wb[64 * 264];
    const int t = threadIdx.x;
    const int hp = blockIdx.x & 3, tl = (blockIdx.x >> 2) & 31, b = blockIdx.x >> 7;
    const int n0 = tl * 64;

    #pragma unroll
    for (int p = 0; p < 16; ++p) {       // x: 1KB contiguous per instr
        int flat = p * 1024 + t * 4;
        int row = flat >> 8, col = flat & 255;
        f32x4 g = *(const f32x4*)&x[((size_t)(b * NN + n0 + row)) * INF + col];
        unsigned a0 = __float_as_uint(g[0]) + 0x8000u;
        unsigned a1 = __float_as_uint(g[1]) + 0x8000u;
        unsigned a2 = __float_as_uint(g[2]) + 0x8000u;
        unsigned a3 = __float_as_uint(g[3]) + 0x8000u;
        uint2 pk;
        pk.x = __builtin_amdgcn_perm(a1, a0, 0x07060302u);
        pk.y = __builtin_amdgcn_perm(a3, a2, 0x07060302u);
        *(uint2*)&xb[row * 264 + col] = pk;
    }
    #pragma unroll
    for (int p = 0; p < 8; ++p) {        // W: 1KB contiguous per instr
        int flat = p * 2048 + t * 8;
        int cc = flat >> 8, f = flat & 255;
        *(short8*)&wb[cc * 264 + f] = *(const short8*)&wT[(hp * 64 + cc) * INF + f];
    }
    __syncthreads();

    const int w = t >> 6, l = t & 63;
    const int ml = l & 15, q = l >> 4;
    f32x4 acc[4] = {};
    const unsigned short* ap = &xb[(w * 16 + ml) * 264 + q * 8];
    #pragma unroll
    for (int k0 = 0; k0 < INF; k0 += 32) {
        short8 A = *(const short8*)&ap[k0];
        #pragma unroll
        for (int c16 = 0; c16 < 4; ++c16) {
            short8 Bf = *(const short8*)&wb[(c16 * 16 + ml) * 264 + q * 8 + k0];
            acc[c16] = __builtin_amdgcn_mfma_f32_16x16x32_bf16(A, Bf, acc[c16], 0, 0, 0);
        }
    }
    __syncthreads();                     // done reading xb

    unsigned short* ldsC = xb;           // [64 col][72 row] (144B stride: 16B-aligned)
    #pragma unroll
    for (int c16 = 0; c16 < 4; ++c16)
        #pragma unroll
        for (int r = 0; r < 4; ++r) {
            int col = c16 * 16 + ml;
            int rt  = w * 16 + q * 4 + r;
            ldsC[col * 72 + rt] = bf16_rhu(acc[c16][r]);
        }
    __syncthreads();

    #pragma unroll
    for (int p = 0; p < 2; ++p) {
        int g = p * 256 + t;             // 0..511
        int d = g & 31, jo = (g >> 5) & 7, h2 = g >> 8;
        short8 vv = *(const short8*)&ldsC[(h2 * 32 + d) * 72 + jo * 8];
        int bh = b * 8 + hp * 2 + h2;
        *(short8*)&whT2[(((size_t)bh * 256 + tl * 8 + jo) * 32 + d) * 8] = vv;
    }
}

// attn: 256 blocks (b, 32-row tile) x 1024 thr; 16 waves = 8 heads x 2 j-halves,
// R=2. p = max(Ej*Ei, Ej5*Ei5). adj bitmask staged depth-3 in a 4-slot ring:
// stage(c+3) issued ~2500 cyc before consume(c) -> HBM latency fully hidden,
// barriers no longer wait on adj loads.
__global__ __launch_bounds__(1024, 4) void attn_kernel(
    const int* __restrict__ adj, const unsigned short* __restrict__ whT2,
    const float* __restrict__ esrc, const unsigned* __restrict__ ejP,
    float* __restrict__ out)
{
    __shared__ __align__(16) unsigned bits[4][2][32][4];   // [slot][half][row][128 bits]
    __shared__ __align__(16) float cmb[8][64][24];
    const int t = threadIdx.x, v = t >> 6, l = t & 63;
    const int h = v & 7, js = v >> 3;
    const int ml = l & 15, q = l >> 4;
    const int it = blockIdx.x & 63, b = blockIdx.x >> 6;
    const int i0 = it * 32;
    const int bh = b * HH + h;

    const float ei0 = esrc[bh * NN + i0 + ml];
    const float ei1 = esrc[bh * NN + i0 + 16 + ml];
    const float Ei0  = __builtin_amdgcn_exp2f(ei0);
    const float Ei05 = __builtin_amdgcn_exp2f(0.2f * ei0);
    const float Ei1  = __builtin_amdgcn_exp2f(ei1);
    const float Ei15 = __builtin_amdgcn_exp2f(0.2f * ei1);

    const unsigned* epP = ejP + bh * NN + js * 1024;
    const unsigned short* whb = whT2 + ((size_t)bh * 256 + js * 128) * 256;

    auto stage = [&](int c2, int buf) {
        #pragma unroll
        for (int u = 0; u < 4; ++u) {
            int uid = v * 4 + u;
            int row = uid & 31, half = uid >> 5;
            const int* g = adj + ((size_t)(b * NN + i0 + row)) * NN
                               + half * 1024 + c2 * 128 + l;
            int a0 = g[0], a1 = g[64];
            unsigned long long m0 = __ballot(a0 != 0);
            unsigned long long m1 = __ballot(a1 != 0);
            if (l == 0) {
                uint4 pv = make_uint4((unsigned)m0, (unsigned)(m0 >> 32),
                                      (unsigned)m1, (unsigned)(m1 >> 32));
                *(uint4*)&bits[buf][half][row][0] = pv;
            }
        }
    };

    const short8 ones = {0x3F80, 0x3F80, 0x3F80, 0x3F80, 0x3F80, 0x3F80, 0x3F80, 0x3F80};
    f32x4 acc00 = {}, acc01 = {}, acc10 = {}, acc11 = {}, accD0 = {}, accD1 = {};

    stage(0, 0);
    stage(1, 1);
    stage(2, 2);
    for (int c = 0; c < 8; ++c) {
        __syncthreads();
        if (c < 5) stage(c + 3, (c + 3) & 3);
        const int buf = c & 3;
        unsigned w0a[4], w1a[4];
        *(uint4*)w0a = *(const uint4*)&bits[buf][js][ml][0];
        *(uint4*)w1a = *(const uint4*)&bits[buf][js][16 + ml][0];
        const unsigned* epc = epP + c * 128;
        #pragma unroll
        for (int k = 0; k < 4; ++k) {
            const int jb = k * 32 + q * 8;
            uint4 epA = *(const uint4*)&epc[jb];
            uint4 epB = *(const uint4*)&epc[jb + 4];
            const unsigned short* wp = whb + (size_t)(c * 16 + k * 4 + q) * 256;
            short8 B0 = *(const short8*)&wp[ml * 8];
            short8 B1 = *(const short8*)&wp[(16 + ml) * 8];
            unsigned st0 = w0a[k] >> (q * 8);
            unsigned st1 = w1a[k] >> (q * 8);
            union { unsigned u[4]; short8 s; } f0, f1;
            const unsigned* ea = &epA.x;
            const unsigned* eb = &epB.x;
            #pragma unroll
            for (int pp = 0; pp < 4; ++pp) {
                unsigned pkA = (pp < 2) ? ea[2 * pp]     : eb[2 * pp - 4];
                unsigned pkB = (pp < 2) ? ea[2 * pp + 1] : eb[2 * pp - 3];
                float EjA = __uint_as_float(pkA & 0xffff0000u);
                float FjA = __uint_as_float(pkA << 16);
                float EjB = __uint_as_float(pkB & 0xffff0000u);
                float FjB = __uint_as_float(pkB << 16);
                unsigned mA0 = (unsigned)__builtin_amdgcn_sbfe(st0, 2 * pp, 1);
                unsigned mB0 = (unsigned)__builtin_amdgcn_sbfe(st0, 2 * pp + 1, 1);
                unsigned mA1 = (unsigned)__builtin_amdgcn_sbfe(st1, 2 * pp, 1);
                unsigned mB1 = (unsigned)__builtin_amdgcn_sbfe(st1, 2 * pp + 1, 1);
                float pA0 = fmaxf(EjA * Ei0, FjA * Ei05);
                float pB0 = fmaxf(EjB * Ei0, FjB * Ei05);
                float pA1 = fmaxf(EjA * Ei1, FjA * Ei15);
                float pB1 = fmaxf(EjB * Ei1, FjB * Ei15);
                f0.u[pp] = __builtin_amdgcn_perm(__float_as_uint(pB0) & mB0,
                                                 __float_as_uint(pA0) & mA0,
                                                 0x07060302u);
                f1.u[pp] = __builtin_amdgcn_perm(__float_as_uint(pB1) & mB1,
                                                 __float_as_uint(pA1) & mA1,
                                                 0x07060302u);
            }
            acc00 = __builtin_amdgcn_mfma_f32_16x16x32_bf16(f0.s, B0, acc00, 0, 0, 0);
            acc01 = __builtin_amdgcn_mfma_f32_16x16x32_bf16(f0.s, B1, acc01, 0, 0, 0);
            accD0 = __builtin_amdgcn_mfma_f32_16x16x32_bf16(f0.s, ones, accD0, 0, 0, 0);
            acc10 = __builtin_amdgcn_mfma_f32_16x16x32_bf16(f1.s, B0, acc10, 0, 0, 0);
            acc11 = __builtin_amdgcn_mfma_f32_16x16x32_bf16(f1.s, B1, acc11, 0, 0, 0);
            accD1 = __builtin_amdgcn_mfma_f32_16x16x32_bf16(f1.s, ones, accD1, 0, 0, 0);
        }
    }

    float* myc = &cmb[h][l][0];
    if (js == 1) {
        *(f32x4*)&myc[0]  = acc00; *(f32x4*)&myc[4]  = acc01;
        *(f32x4*)&myc[8]  = acc10; *(f32x4*)&myc[12] = acc11;
        *(f32x4*)&myc[16] = accD0; *(f32x4*)&myc[20] = accD1;
    }
    __syncthreads();
    if (js == 0) {
        f32x4 o00 = *(const f32x4*)&myc[0],  o01 = *(const f32x4*)&myc[4];
        f32x4 o10 = *(const f32x4*)&myc[8],  o11 = *(const f32x4*)&myc[12];
        f32x4 oD0 = *(const f32x4*)&myc[16], oD1 = *(const f32x4*)&myc[20];
        #pragma unroll
        for (int r = 0; r < 4; ++r) {
            int ir0 = i0 + q * 4 + r;
            int ir1 = i0 + 16 + q * 4 + r;
            float inv0 = 1.0f / (accD0[r] + oD0[r]);
            float inv1 = 1.0f / (accD1[r] + oD1[r]);
            size_t ba0 = ((size_t)(b * NN + ir0)) * (HH * DD) + h * DD;
            size_t ba1 = ((size_t)(b * NN + ir1)) * (HH * DD) + h * DD;
            out[ba0 + ml]      = (acc00[r] + o00[r]) * inv0;
            out[ba0 + 16 + ml] = (acc01[r] + o01[r]) * inv0;
            out[ba1 + ml]      = (acc10[r] + o10[r]) * inv1;
            out[ba1 + 16 + ml] = (acc11[r] + o11[r]) * inv1;
        }
    }
}

extern "C" void kernel_launch(void* const* d_in, const int* in_sizes, int n_in,
                              void* d_out, int out_size, void* d_ws, size_t ws_size,
                              hipStream_t stream) {
    (void)in_sizes; (void)n_in; (void)out_size; (void)ws_size;
    const float* x   = (const float*)d_in[0];
    const int*   adj = (const int*)d_in[1];
    const float* W   = (const float*)d_in[2];
    const float* a   = (const float*)d_in[3];
    float* out = (float*)d_out;

    char* ws = (char*)d_ws;
    unsigned short* whT2 = (unsigned short*)ws;                         // 4 MB
    unsigned short* wT   = (unsigned short*)(ws + (4u << 20));          // 128 KB
    float*    esrc = (float*)(ws + (4u << 20) + (128u << 10));          // 256 KB
    unsigned* ejP  = (unsigned*)(esrc + BB * HH * NN);                  // 256 KB
    float*    we_g = (float*)(ejP + BB * HH * NN);                      // 16 KB

    wprep_kernel<<<dim3(32),  dim3(256), 0, stream>>>(W, a, we_g, wT);
    ek_kernel  <<<dim3(512),  dim3(256), 0, stream>>>(x, we_g, esrc, ejP);
    whk_kernel <<<dim3(512),  dim3(256), 0, stream>>>(x, wT, whT2);
    attn_kernel<<<dim3(256),  dim3(1024), 0, stream>>>(adj, whT2, esrc, ejP, out);
}

// Round 9
// 148.167 us; speedup vs baseline: 1.0705x; 1.0705x over previous
//
#include <hip/hip_runtime.h>

#define BB 4
#define NN 2048
#define INF 256
#define HH 8
#define DD 32
#define LOG2E 1.4426950408889634f

typedef __attribute__((ext_vector_type(8))) short short8;
typedef __attribute__((ext_vector_type(4))) float f32x4;

__device__ __forceinline__ unsigned short bf16_rne(float v) {
    unsigned b = __float_as_uint(v);
    return (unsigned short)((b + 0x7fffu + ((b >> 16) & 1u)) >> 16);
}
__device__ __forceinline__ unsigned short bf16_rhu(float v) {
    return (unsigned short)((__float_as_uint(v) + 0x8000u) >> 16);
}

// wprep: we_g[16][256] fp32 (log2-scaled) + wT bf16 [h*32+d][f]. grid 32 x 256.
__global__ __launch_bounds__(256) void wprep_kernel(
    const float* __restrict__ W, const float* __restrict__ a,
    float* __restrict__ we_g, unsigned short* __restrict__ wT)
{
    const int bb = blockIdx.x, t = threadIdx.x;
    if (bb < 16) {           // we part: k = bb
        const int h = bb & 7, sel = bb >> 3;
        const float* wr = W + ((size_t)(h * INF + t)) * DD;
        const float* av = a + h * 2 * DD + sel * DD;
        float acc = 0.f;
        #pragma unroll
        for (int d = 0; d < DD; ++d) acc += wr[d] * av[d];
        we_g[bb * INF + t] = acc * LOG2E;
    }
    #pragma unroll
    for (int r2 = 0; r2 < 8; ++r2) {      // wT rows bb*8 .. bb*8+8
        int row = bb * 8 + r2;
        int h = row >> 5, d = row & 31;
        wT[row * INF + t] = bf16_rhu(W[((size_t)(h * INF + t)) * DD + d]);
    }
}

// ek: exact fp32 e-dots. 16-row tiles, grid 512 x 256.
// esrc raw (log2-scaled); ejP = pack(bf16(exp2(ej)), bf16(exp2(0.2 ej))).
__global__ __launch_bounds__(256) void ek_kernel(
    const float* __restrict__ x, const float* __restrict__ we_g,
    float* __restrict__ esrc, unsigned* __restrict__ ejP)
{
    __shared__ __align__(16) float xs[16 * 260];       // [row][f] pad 260
    __shared__ __align__(16) float weld2[16 * 260];    // [c][k*16+fi] pad 260
    const int t = threadIdx.x;
    const int tile = blockIdx.x & 127, b = blockIdx.x >> 7;
    const int n0 = tile * 16;

    #pragma unroll
    for (int p = 0; p < 4; ++p) {        // x tile: fully coalesced 1KB/instr
        int flat = p * 1024 + t * 4;
        int row = flat >> 8, col = flat & 255;
        f32x4 g = *(const f32x4*)&x[((size_t)(b * NN + n0 + row)) * INF + col];
        *(f32x4*)&xs[row * 260 + col] = g;
    }
    #pragma unroll
    for (int p = 0; p < 4; ++p) {        // weld2[c][k][fi]
        int flat = p * 1024 + t * 4;
        int k = flat >> 8, f = flat & 255;
        f32x4 g = *(const f32x4*)&we_g[flat];
        *(f32x4*)&weld2[(f >> 4) * 260 + k * 16 + (f & 15)] = g;
    }
    __syncthreads();

    const int row = t >> 4, c = t & 15;
    f32x4 xv[4];
    #pragma unroll
    for (int i = 0; i < 4; ++i)
        xv[i] = *(const f32x4*)&xs[row * 260 + c * 16 + i * 4];

    float keep = 0.f;
    #pragma unroll
    for (int k = 0; k < 16; ++k) {
        float s = 0.f;
        #pragma unroll
        for (int i = 0; i < 4; ++i) {
            f32x4 w4 = *(const f32x4*)&weld2[c * 260 + k * 16 + i * 4];
            s += xv[i][0]*w4[0] + xv[i][1]*w4[1] + xv[i][2]*w4[2] + xv[i][3]*w4[3];
        }
        s += __shfl_xor(s, 1, 64);
        s += __shfl_xor(s, 2, 64);
        s += __shfl_xor(s, 4, 64);
        s += __shfl_xor(s, 8, 64);
        keep = (c == k) ? s : keep;
    }
    const int n = n0 + row;
    if (c < 8) {
        esrc[(b * 8 + c) * NN + n] = keep;
    } else {
        float Ej  = __builtin_amdgcn_exp2f(keep);
        float Ej5 = __builtin_amdgcn_exp2f(0.2f * keep);
        ejP[(b * 8 + (c - 8)) * NN + n] =
            ((unsigned)bf16_rne(Ej) << 16) | (unsigned)bf16_rne(Ej5);
    }
}

// whk: 64 rows x 64 cols (2 heads) x K=256 MFMA GEMM, fp32 x converted in staging.
// output whT2[bh][j/8][d][8] bf16. grid 512 x 256.
__global__ __launch_bounds__(256) void whk_kernel(
    const float* __restrict__ x, const unsigned short* __restrict__ wT,
    unsigned short* __restrict__ whT2)
{
    __shared__ __align__(16) unsigned short xb[64 * 264];
    __shared__ __align__(16) unsigned short wb[64 * 264];
    const int t = threadIdx.x;
    const int hp = blockIdx.x & 3, tl = (blockIdx.x >> 2) & 31, b = blockIdx.x >> 7;
    const int n0 = tl * 64;

    #pragma unroll
    for (int p = 0; p < 16; ++p) {       // x: 1KB contiguous per instr
        int flat = p * 1024 + t * 4;
        int row = flat >> 8, col = flat & 255;
        f32x4 g = *(const f32x4*)&x[((size_t)(b * NN + n0 + row)) * INF + col];
        unsigned a0 = __float_as_uint(g[0]) + 0x8000u;
        unsigned a1 = __float_as_uint(g[1]) + 0x8000u;
        unsigned a2 = __float_as_uint(g[2]) + 0x8000u;
        unsigned a3 = __float_as_uint(g[3]) + 0x8000u;
        uint2 pk;
        pk.x = __builtin_amdgcn_perm(a1, a0, 0x07060302u);
        pk.y = __builtin_amdgcn_perm(a3, a2, 0x07060302u);
        *(uint2*)&xb[row * 264 + col] = pk;
    }
    #pragma unroll
    for (int p = 0; p < 8; ++p) {        // W: 1KB contiguous per instr
        int flat = p * 2048 + t * 8;
        int cc = flat >> 8, f = flat & 255;
        *(short8*)&wb[cc * 264 + f] = *(const short8*)&wT[(hp * 64 + cc) * INF + f];
    }
    __syncthreads();

    const int w = t >> 6, l = t & 63;
    const int ml = l & 15, q = l >> 4;
    f32x4 acc[4] = {};
    const unsigned short* ap = &xb[(w * 16 + ml) * 264 + q * 8];
    #pragma unroll
    for (int k0 = 0; k0 < INF; k0 += 32) {
        short8 A = *(const short8*)&ap[k0];
        #pragma unroll
        for (int c16 = 0; c16 < 4; ++c16) {
            short8 Bf = *(const short8*)&wb[(c16 * 16 + ml) * 264 + q * 8 + k0];
            acc[c16] = __builtin_amdgcn_mfma_f32_16x16x32_bf16(A, Bf, acc[c16], 0, 0, 0);
        }
    }
    __syncthreads();                     // done reading xb

    unsigned short* ldsC = xb;           // [64 col][72 row]
    #pragma unroll
    for (int c16 = 0; c16 < 4; ++c16)
        #pragma unroll
        for (int r = 0; r < 4; ++r) {
            int col = c16 * 16 + ml;
            int rt  = w * 16 + q * 4 + r;
            ldsC[col * 72 + rt] = bf16_rhu(acc[c16][r]);
        }
    __syncthreads();

    #pragma unroll
    for (int p = 0; p < 2; ++p) {
        int g = p * 256 + t;             // 0..511
        int d = g & 31, jo = (g >> 5) & 7, h2 = g >> 8;
        short8 vv = *(const short8*)&ldsC[(h2 * 32 + d) * 72 + jo * 8];
        int bh = b * 8 + hp * 2 + h2;
        *(short8*)&whT2[(((size_t)bh * 256 + tl * 8 + jo) * 32 + d) * 8] = vv;
    }
}

// attn: 256 blocks (b, 32-row tile) x 1024 thr; 16 waves = 8 heads x 2 j-halves,
// R=2. p = max(Ej*Ei, Ej5*Ei5). adj pipeline DECOUPLED: stage_load (global->VGPR,
// no wait) at iter c-1, stage_commit (ballot+LDS) at iter c -> the vmcnt wait
// lands on chunk-old loads, not fresh ones. 2 LDS slots ping-pong.
__global__ __launch_bounds__(1024, 4) void attn_kernel(
    const int* __restrict__ adj, const unsigned short* __restrict__ whT2,
    const float* __restrict__ esrc, const unsigned* __restrict__ ejP,
    float* __restrict__ out)
{
    __shared__ __align__(16) unsigned bits[2][2][32][4];   // [slot][half][row][128 bits]
    __shared__ __align__(16) float cmb[8][64][25];         // stride 25: no bank alias
    const int t = threadIdx.x, v = t >> 6, l = t & 63;
    const int h = v & 7, js = v >> 3;
    const int ml = l & 15, q = l >> 4;
    const int it = blockIdx.x & 63, b = blockIdx.x >> 6;
    const int i0 = it * 32;
    const int bh = b * HH + h;

    const float ei0 = esrc[bh * NN + i0 + ml];
    const float ei1 = esrc[bh * NN + i0 + 16 + ml];
    const float Ei0  = __builtin_amdgcn_exp2f(ei0);
    const float Ei05 = __builtin_amdgcn_exp2f(0.2f * ei0);
    const float Ei1  = __builtin_amdgcn_exp2f(ei1);
    const float Ei15 = __builtin_amdgcn_exp2f(0.2f * ei1);

    const unsigned* epP = ejP + bh * NN + js * 1024;
    const unsigned short* whb = whT2 + ((size_t)bh * 256 + js * 128) * 256;

    // adj base rows for this wave's 4 staging units
    const int* gbase[4];
    #pragma unroll
    for (int u = 0; u < 4; ++u) {
        int uid = v * 4 + u;
        int row = uid & 31, half = uid >> 5;
        gbase[u] = adj + ((size_t)(b * NN + i0 + row)) * NN + half * 1024 + l;
    }

    auto stage_load = [&](int c2, int* ra, int* rb) {
        #pragma unroll
        for (int u = 0; u < 4; ++u) {
            const int* g = gbase[u] + c2 * 128;
            ra[u] = g[0];
            rb[u] = g[64];
        }
    };
    auto stage_commit = [&](const int* ra, const int* rb, int buf) {
        #pragma unroll
        for (int u = 0; u < 4; ++u) {
            int uid = v * 4 + u;
            int row = uid & 31, half = uid >> 5;
            unsigned long long m0 = __ballot(ra[u] != 0);
            unsigned long long m1 = __ballot(rb[u] != 0);
            if (l == 0) {
                uint4 pv = make_uint4((unsigned)m0, (unsigned)(m0 >> 32),
                                      (unsigned)m1, (unsigned)(m1 >> 32));
                *(uint4*)&bits[buf][half][row][0] = pv;
            }
        }
    };

    const short8 ones = {0x3F80, 0x3F80, 0x3F80, 0x3F80, 0x3F80, 0x3F80, 0x3F80, 0x3F80};
    f32x4 acc00 = {}, acc01 = {}, acc10 = {}, acc11 = {}, accD0 = {}, accD1 = {};

    int rA0[4], rA1[4], rB0[4], rB1[4];
    stage_load(0, rA0, rA1);
    stage_load(1, rB0, rB1);
    stage_commit(rA0, rA1, 0);           // only unavoidable fresh-load wait

    for (int c = 0; c < 8; ++c) {
        __syncthreads();
        // commit chunk c+1 (regs loaded at iter c-1), then issue load c+2
        if (c < 7) {
            if (c & 1) stage_commit(rA0, rA1, (c + 1) & 1);
            else       stage_commit(rB0, rB1, (c + 1) & 1);
        }
        if (c < 6) {
            if (c & 1) stage_load(c + 2, rB0, rB1);
            else       stage_load(c + 2, rA0, rA1);
        }
        const int buf = c & 1;
        unsigned w0a[4], w1a[4];
        *(uint4*)w0a = *(const uint4*)&bits[buf][js][ml][0];
        *(uint4*)w1a = *(const uint4*)&bits[buf][js][16 + ml][0];
        const unsigned* epc = epP + c * 128;
        #pragma unroll
        for (int k = 0; k < 4; ++k) {
            const int jb = k * 32 + q * 8;
            uint4 epA = *(const uint4*)&epc[jb];
            uint4 epB = *(const uint4*)&epc[jb + 4];
            const unsigned short* wp = whb + (size_t)(c * 16 + k * 4 + q) * 256;
            short8 B0 = *(const short8*)&wp[ml * 8];
            short8 B1 = *(const short8*)&wp[(16 + ml) * 8];
            unsigned st0 = w0a[k] >> (q * 8);
            unsigned st1 = w1a[k] >> (q * 8);
            union { unsigned u[4]; short8 s; } f0, f1;
            const unsigned* ea = &epA.x;
            const unsigned* eb = &epB.x;
            #pragma unroll
            for (int pp = 0; pp < 4; ++pp) {
                unsigned pkA = (pp < 2) ? ea[2 * pp]     : eb[2 * pp - 4];
                unsigned pkB = (pp < 2) ? ea[2 * pp + 1] : eb[2 * pp - 3];
                float EjA = __uint_as_float(pkA & 0xffff0000u);
                float FjA = __uint_as_float(pkA << 16);
                float EjB = __uint_as_float(pkB & 0xffff0000u);
                float FjB = __uint_as_float(pkB << 16);
                unsigned mA0 = (unsigned)__builtin_amdgcn_sbfe(st0, 2 * pp, 1);
                unsigned mB0 = (unsigned)__builtin_amdgcn_sbfe(st0, 2 * pp + 1, 1);
                unsigned mA1 = (unsigned)__builtin_amdgcn_sbfe(st1, 2 * pp, 1);
                unsigned mB1 = (unsigned)__builtin_amdgcn_sbfe(st1, 2 * pp + 1, 1);
                float pA0 = fmaxf(EjA * Ei0, FjA * Ei05);
                float pB0 = fmaxf(EjB * Ei0, FjB * Ei05);
                float pA1 = fmaxf(EjA * Ei1, FjA * Ei15);
                float pB1 = fmaxf(EjB * Ei1, FjB * Ei15);
                f0.u[pp] = __builtin_amdgcn_perm(__float_as_uint(pB0) & mB0,
                                                 __float_as_uint(pA0) & mA0,
                                                 0x07060302u);
                f1.u[pp] = __builtin_amdgcn_perm(__float_as_uint(pB1) & mB1,
                                                 __float_as_uint(pA1) & mA1,
                                                 0x07060302u);
            }
            acc00 = __builtin_amdgcn_mfma_f32_16x16x32_bf16(f0.s, B0, acc00, 0, 0, 0);
            acc01 = __builtin_amdgcn_mfma_f32_16x16x32_bf16(f0.s, B1, acc01, 0, 0, 0);
            accD0 = __builtin_amdgcn_mfma_f32_16x16x32_bf16(f0.s, ones, accD0, 0, 0, 0);
            acc10 = __builtin_amdgcn_mfma_f32_16x16x32_bf16(f1.s, B0, acc10, 0, 0, 0);
            acc11 = __builtin_amdgcn_mfma_f32_16x16x32_bf16(f1.s, B1, acc11, 0, 0, 0);
            accD1 = __builtin_amdgcn_mfma_f32_16x16x32_bf16(f1.s, ones, accD1, 0, 0, 0);
        }
    }

    float* myc = &cmb[h][l][0];
    if (js == 1) {
        *(f32x4*)&myc[0]  = acc00; *(f32x4*)&myc[4]  = acc01;
        *(f32x4*)&myc[8]  = acc10; *(f32x4*)&myc[12] = acc11;
        *(f32x4*)&myc[16] = accD0; *(f32x4*)&myc[20] = accD1;
    }
    __syncthreads();
    if (js == 0) {
        f32x4 o00 = *(const f32x4*)&myc[0],  o01 = *(const f32x4*)&myc[4];
        f32x4 o10 = *(const f32x4*)&myc[8],  o11 = *(const f32x4*)&myc[12];
        f32x4 oD0 = *(const f32x4*)&myc[16], oD1 = *(const f32x4*)&myc[20];
        #pragma unroll
        for (int r = 0; r < 4; ++r) {
            int ir0 = i0 + q * 4 + r;
            int ir1 = i0 + 16 + q * 4 + r;
            float inv0 = 1.0f / (accD0[r] + oD0[r]);
            float inv1 = 1.0f / (accD1[r] + oD1[r]);
            size_t ba0 = ((size_t)(b * NN + ir0)) * (HH * DD) + h * DD;
            size_t ba1 = ((size_t)(b * NN + ir1)) * (HH * DD) + h * DD;
            out[ba0 + ml]      = (acc00[r] + o00[r]) * inv0;
            out[ba0 + 16 + ml] = (acc01[r] + o01[r]) * inv0;
            out[ba1 + ml]      = (acc10[r] + o10[r]) * inv1;
            out[ba1 + 16 + ml] = (acc11[r] + o11[r]) * inv1;
        }
    }
}

extern "C" void kernel_launch(void* const* d_in, const int* in_sizes, int n_in,
                              void* d_out, int out_size, void* d_ws, size_t ws_size,
                              hipStream_t stream) {
    (void)in_sizes; (void)n_in; (void)out_size; (void)ws_size;
    const float* x   = (const float*)d_in[0];
    const int*   adj = (const int*)d_in[1];
    const float* W   = (const float*)d_in[2];
    const float* a   = (const float*)d_in[3];
    float* out = (float*)d_out;

    char* ws = (char*)d_ws;
    unsigned short* whT2 = (unsigned short*)ws;                         // 4 MB
    unsigned short* wT   = (unsigned short*)(ws + (4u << 20));          // 128 KB
    float*    esrc = (float*)(ws + (4u << 20) + (128u << 10));          // 256 KB
    unsigned* ejP  = (unsigned*)(esrc + BB * HH * NN);                  // 256 KB
    float*    we_g = (float*)(ejP + BB * HH * NN);                      // 16 KB

    wprep_kernel<<<dim3(32),  dim3(256), 0, stream>>>(W, a, we_g, wT);
    ek_kernel  <<<dim3(512),  dim3(256), 0, stream>>>(x, we_g, esrc, ejP);
    whk_kernel <<<dim3(512),  dim3(256), 0, stream>>>(x, wT, whT2);
    attn_kernel<<<dim3(256),  dim3(1024), 0, stream>>>(adj, whT2, esrc, ejP, out);
}